// Round 1
// baseline (433.701 us; speedup 1.0000x reference)
//
#include <hip/hip_runtime.h>
#include <math.h>

#define NBATCH 32
#define NCH 16
#define HW 65536
#define SLICES 32
#define TPB 256

// ws layout (floats)
#define WS_SUMS_S 0      // [b][cls][ch] -> b*32 + cls*16 + ch   (1024)
#define WS_SUMS_T 1024   // (1024)
#define WS_N1     2048   // per-batch class-1 pixel count (32)
#define WS_LOSS   2080   // scalar accumulator
#define WS_FLOATS 2112

__device__ __forceinline__ float wave_sum(float v) {
#pragma unroll
  for (int off = 32; off > 0; off >>= 1) v += __shfl_down(v, off, 64);
  return v;
}

__global__ __launch_bounds__(TPB) void k_pass1(const float* __restrict__ S,
                                               const float* __restrict__ T,
                                               const int* __restrict__ tgt,
                                               float* __restrict__ ws) {
  const int b = blockIdx.y;
  const int slice = blockIdx.x;
  const int tid = threadIdx.x;
  const int pxb = HW / SLICES;  // 2048
  const int base = slice * pxb;

  const float* Sb = S + (size_t)b * NCH * HW;
  const float* Tb = T + (size_t)b * NCH * HW;
  const int* tb = tgt + (size_t)b * HW;

  float aS0[NCH], aS1[NCH], aT0[NCH], aT1[NCH];
#pragma unroll
  for (int c = 0; c < NCH; ++c) { aS0[c] = 0.f; aS1[c] = 0.f; aT0[c] = 0.f; aT1[c] = 0.f; }
  float n1 = 0.f;

  const int iters = pxb / (TPB * 2);  // 4
  for (int it = 0; it < iters; ++it) {
    const int p = base + (it * TPB + tid) * 2;
    const int2 tv = *(const int2*)(tb + p);
    const float m0 = (tv.x == 1) ? 1.f : 0.f;
    const float m1 = (tv.y == 1) ? 1.f : 0.f;
    n1 += m0 + m1;

    float2 x[NCH];
    // ---- S ----
#pragma unroll
    for (int c = 0; c < NCH; ++c) x[c] = *(const float2*)(Sb + (size_t)c * HW + p);
    float ss0 = 0.f, ss1 = 0.f;
#pragma unroll
    for (int c = 0; c < NCH; ++c) {
      ss0 = fmaf(x[c].x, x[c].x, ss0);
      ss1 = fmaf(x[c].y, x[c].y, ss1);
    }
    float i0 = 1.f / fmaxf(sqrtf(ss0), 1e-12f);
    float i1 = 1.f / fmaxf(sqrtf(ss1), 1e-12f);
#pragma unroll
    for (int c = 0; c < NCH; ++c) {
      float f0 = x[c].x * i0, f1 = x[c].y * i1;
      aS0[c] += f0 + f1;                              // total (class0 = total - class1)
      aS1[c] = fmaf(f0, m0, fmaf(f1, m1, aS1[c]));    // class-1 masked
    }
    // ---- T ----
#pragma unroll
    for (int c = 0; c < NCH; ++c) x[c] = *(const float2*)(Tb + (size_t)c * HW + p);
    ss0 = 0.f; ss1 = 0.f;
#pragma unroll
    for (int c = 0; c < NCH; ++c) {
      ss0 = fmaf(x[c].x, x[c].x, ss0);
      ss1 = fmaf(x[c].y, x[c].y, ss1);
    }
    i0 = 1.f / fmaxf(sqrtf(ss0), 1e-12f);
    i1 = 1.f / fmaxf(sqrtf(ss1), 1e-12f);
#pragma unroll
    for (int c = 0; c < NCH; ++c) {
      float f0 = x[c].x * i0, f1 = x[c].y * i1;
      aT0[c] += f0 + f1;
      aT1[c] = fmaf(f0, m0, fmaf(f1, m1, aT1[c]));
    }
  }

  // totals -> class-0 sums
#pragma unroll
  for (int c = 0; c < NCH; ++c) { aS0[c] -= aS1[c]; aT0[c] -= aT1[c]; }

  // per-wave reduction, then one atomic set per wave (65 values)
#pragma unroll
  for (int c = 0; c < NCH; ++c) {
    aS0[c] = wave_sum(aS0[c]);
    aS1[c] = wave_sum(aS1[c]);
    aT0[c] = wave_sum(aT0[c]);
    aT1[c] = wave_sum(aT1[c]);
  }
  n1 = wave_sum(n1);

  if ((tid & 63) == 0) {
    float* dS = ws + WS_SUMS_S + b * 32;
    float* dT = ws + WS_SUMS_T + b * 32;
#pragma unroll
    for (int c = 0; c < NCH; ++c) {
      atomicAdd(dS + c, aS0[c]);
      atomicAdd(dS + 16 + c, aS1[c]);
      atomicAdd(dT + c, aT0[c]);
      atomicAdd(dT + 16 + c, aT1[c]);
    }
    atomicAdd(ws + WS_N1 + b, n1);
  }
}

// per-pixel pcsim given ss, raw dots vs class means, target, mean norms
__device__ __forceinline__ float pc_one(float ss, float d0, float d1, int t,
                                        float nm0, float nm1) {
  float n = sqrtf(ss);
  float inv = 1.f / fmaxf(n, 1e-12f);
  float na = n * inv;  // == |feat|
  float c0 = (d0 * inv) / fmaxf(na * nm0, 1e-8f);
  float c1 = (d1 * inv) / fmaxf(na * nm1, 1e-8f);
  return expf((t == 1) ? (c1 - c0) : (c0 - c1));
}

__global__ __launch_bounds__(TPB) void k_pass2(const float* __restrict__ S,
                                               const float* __restrict__ T,
                                               const int* __restrict__ tgt,
                                               float* __restrict__ ws) {
  __shared__ float sm[68];  // [0..63] means (S0,S1,T0,T1 x 16ch), [64..67] norms
  const int b = blockIdx.y;
  const int slice = blockIdx.x;
  const int tid = threadIdx.x;

  if (tid < 64) {
    int t = tid >> 5;          // 0=S 1=T
    int cls = (tid >> 4) & 1;
    int ch = tid & 15;
    float n1v = ws[WS_N1 + b];
    float cnt = (cls ? n1v : ((float)HW - n1v)) + 1e-6f;
    float s = ws[(t ? WS_SUMS_T : WS_SUMS_S) + b * 32 + cls * 16 + ch];
    sm[tid] = s / cnt;
  }
  __syncthreads();
  if (tid < 4) {  // tid = t*2+cls
    float ss = 0.f;
    int base_ = (tid >> 1) * 32 + (tid & 1) * 16;
#pragma unroll
    for (int c = 0; c < NCH; ++c) { float v = sm[base_ + c]; ss = fmaf(v, v, ss); }
    sm[64 + tid] = sqrtf(ss);
  }
  __syncthreads();

  const int pxb = HW / SLICES;
  const int base = slice * pxb;
  const float* Sb = S + (size_t)b * NCH * HW;
  const float* Tb = T + (size_t)b * NCH * HW;
  const int* tb = tgt + (size_t)b * HW;

  const float nmS0 = sm[64], nmS1 = sm[65], nmT0 = sm[66], nmT1 = sm[67];

  float lacc = 0.f;
  const int iters = pxb / (TPB * 4);  // 2
  for (int it = 0; it < iters; ++it) {
    const int p = base + (it * TPB + tid) * 4;
    const int4 tv = *(const int4*)(tb + p);

    // ---- S: fused ss + dots (inv_norm factored out of the dot) ----
    float4 ssv = {0, 0, 0, 0}, d0 = {0, 0, 0, 0}, d1 = {0, 0, 0, 0};
#pragma unroll
    for (int c = 0; c < NCH; ++c) {
      float4 x = *(const float4*)(Sb + (size_t)c * HW + p);
      float w0 = sm[c], w1 = sm[16 + c];
      ssv.x = fmaf(x.x, x.x, ssv.x); ssv.y = fmaf(x.y, x.y, ssv.y);
      ssv.z = fmaf(x.z, x.z, ssv.z); ssv.w = fmaf(x.w, x.w, ssv.w);
      d0.x = fmaf(x.x, w0, d0.x); d0.y = fmaf(x.y, w0, d0.y);
      d0.z = fmaf(x.z, w0, d0.z); d0.w = fmaf(x.w, w0, d0.w);
      d1.x = fmaf(x.x, w1, d1.x); d1.y = fmaf(x.y, w1, d1.y);
      d1.z = fmaf(x.z, w1, d1.z); d1.w = fmaf(x.w, w1, d1.w);
    }
    float pcS0 = pc_one(ssv.x, d0.x, d1.x, tv.x, nmS0, nmS1);
    float pcS1 = pc_one(ssv.y, d0.y, d1.y, tv.y, nmS0, nmS1);
    float pcS2 = pc_one(ssv.z, d0.z, d1.z, tv.z, nmS0, nmS1);
    float pcS3 = pc_one(ssv.w, d0.w, d1.w, tv.w, nmS0, nmS1);

    // ---- T ----
    ssv = {0, 0, 0, 0}; d0 = {0, 0, 0, 0}; d1 = {0, 0, 0, 0};
#pragma unroll
    for (int c = 0; c < NCH; ++c) {
      float4 x = *(const float4*)(Tb + (size_t)c * HW + p);
      float w0 = sm[32 + c], w1 = sm[48 + c];
      ssv.x = fmaf(x.x, x.x, ssv.x); ssv.y = fmaf(x.y, x.y, ssv.y);
      ssv.z = fmaf(x.z, x.z, ssv.z); ssv.w = fmaf(x.w, x.w, ssv.w);
      d0.x = fmaf(x.x, w0, d0.x); d0.y = fmaf(x.y, w0, d0.y);
      d0.z = fmaf(x.z, w0, d0.z); d0.w = fmaf(x.w, w0, d0.w);
      d1.x = fmaf(x.x, w1, d1.x); d1.y = fmaf(x.y, w1, d1.y);
      d1.z = fmaf(x.z, w1, d1.z); d1.w = fmaf(x.w, w1, d1.w);
    }
    float pcT0 = pc_one(ssv.x, d0.x, d1.x, tv.x, nmT0, nmT1);
    float pcT1 = pc_one(ssv.y, d0.y, d1.y, tv.y, nmT0, nmT1);
    float pcT2 = pc_one(ssv.z, d0.z, d1.z, tv.z, nmT0, nmT1);
    float pcT3 = pc_one(ssv.w, d0.w, d1.w, tv.w, nmT0, nmT1);

    float e0 = pcS0 - pcT0, e1 = pcS1 - pcT1, e2 = pcS2 - pcT2, e3 = pcS3 - pcT3;
    lacc += e0 * e0 + e1 * e1 + e2 * e2 + e3 * e3;
  }

  lacc = wave_sum(lacc);
  if ((tid & 63) == 0) atomicAdd(ws + WS_LOSS, lacc);
}

__global__ void k_final(const float* __restrict__ ws, float* __restrict__ out) {
  out[0] = ws[WS_LOSS] * (1.f / 2097152.f);  // N = 32*256*256 = 2^21, exact
}

extern "C" void kernel_launch(void* const* d_in, const int* in_sizes, int n_in,
                              void* d_out, int out_size, void* d_ws, size_t ws_size,
                              hipStream_t stream) {
  const float* S = (const float*)d_in[0];
  const float* T = (const float*)d_in[1];
  const int* tgt = (const int*)d_in[2];
  float* ws = (float*)d_ws;
  float* out = (float*)d_out;

  hipMemsetAsync(d_ws, 0, WS_FLOATS * sizeof(float), stream);
  dim3 grid(SLICES, NBATCH);
  k_pass1<<<grid, TPB, 0, stream>>>(S, T, tgt, ws);
  k_pass2<<<grid, TPB, 0, stream>>>(S, T, tgt, ws);
  k_final<<<1, 1, 0, stream>>>(ws, out);
}

// Round 2
// 337.060 us; speedup vs baseline: 1.2867x; 1.2867x over previous
//
#include <hip/hip_runtime.h>
#include <math.h>

#define NBATCH 32
#define NCH 16
#define HW 65536
#define SLICES1 32   // k_sums: blocks per (batch,tensor)
#define SLICES2 64   // k_pass2: blocks per batch
#define TPB 256

// ws layout (floats)
#define WS_SUMS_S 0      // [b][cls][ch] -> b*32 + cls*16 + ch   (1024)
#define WS_SUMS_T 1024   // (1024)
#define WS_N1     2048   // per-batch class-1 pixel count (32)
#define WS_LOSS   2080   // per-batch loss partials (32)
#define WS_FLOATS 2112

__device__ __forceinline__ float wave_sum(float v) {
#pragma unroll
  for (int off = 32; off > 0; off >>= 1) v += __shfl_down(v, off, 64);
  return v;
}

// grid (SLICES1, NBATCH, 2). z=0 -> S, z=1 -> T.
// Per-tensor accumulation: 32 live accumulators + 32 x-regs, no spill.
__global__ __launch_bounds__(TPB) void k_sums(const float* __restrict__ S,
                                              const float* __restrict__ T,
                                              const int* __restrict__ tgt,
                                              float* __restrict__ ws) {
  const int b = blockIdx.y;
  const int slice = blockIdx.x;
  const int which = blockIdx.z;  // uniform
  const int tid = threadIdx.x;
  const int lane = tid & 63, wid = tid >> 6;

  const float* Xb = (which ? T : S) + (size_t)b * NCH * HW;
  const int* tb = tgt + (size_t)b * HW;
  float* dst = ws + (which ? WS_SUMS_T : WS_SUMS_S) + b * 32;

  float tot[NCH], c1[NCH];
#pragma unroll
  for (int c = 0; c < NCH; ++c) { tot[c] = 0.f; c1[c] = 0.f; }
  float n1 = 0.f;

  const int pxb = HW / SLICES1;           // 2048
  const int base = slice * pxb;
  const int iters = pxb / (TPB * 2);      // 4

  for (int it = 0; it < iters; ++it) {
    const int p = base + (it * TPB + tid) * 2;
    const int2 tv = *(const int2*)(tb + p);
    const float m0 = (tv.x == 1) ? 1.f : 0.f;
    const float m1 = (tv.y == 1) ? 1.f : 0.f;
    if (which == 0) n1 += m0 + m1;

    float2 x[NCH];
#pragma unroll
    for (int c = 0; c < NCH; ++c) x[c] = *(const float2*)(Xb + (size_t)c * HW + p);

    // split chains for ILP
    float s0a = 0.f, s0b = 0.f, s1a = 0.f, s1b = 0.f;
#pragma unroll
    for (int c = 0; c < NCH; c += 2) {
      s0a = fmaf(x[c].x, x[c].x, s0a);
      s1a = fmaf(x[c].y, x[c].y, s1a);
      s0b = fmaf(x[c + 1].x, x[c + 1].x, s0b);
      s1b = fmaf(x[c + 1].y, x[c + 1].y, s1b);
    }
    const float i0 = 1.f / fmaxf(sqrtf(s0a + s0b), 1e-12f);
    const float i1 = 1.f / fmaxf(sqrtf(s1a + s1b), 1e-12f);
#pragma unroll
    for (int c = 0; c < NCH; ++c) {
      const float f0 = x[c].x * i0, f1 = x[c].y * i1;
      tot[c] += f0 + f1;                            // total; class0 = total - class1
      c1[c] = fmaf(f0, m0, fmaf(f1, m1, c1[c]));    // class-1 masked
    }
  }

#pragma unroll
  for (int c = 0; c < NCH; ++c) tot[c] -= c1[c];    // -> class-0 sums

#pragma unroll
  for (int c = 0; c < NCH; ++c) { tot[c] = wave_sum(tot[c]); c1[c] = wave_sum(c1[c]); }
  n1 = wave_sum(n1);

  __shared__ float red[4][36];
  if (lane == 0) {
#pragma unroll
    for (int c = 0; c < NCH; ++c) { red[wid][c] = tot[c]; red[wid][16 + c] = c1[c]; }
    red[wid][32] = n1;
  }
  __syncthreads();
  if (tid < 33) {
    const float v = red[0][tid] + red[1][tid] + red[2][tid] + red[3][tid];
    if (tid < 32) atomicAdd(dst + tid, v);          // dst[cls*16+ch]
    else if (which == 0) atomicAdd(ws + WS_N1 + b, v);
  }
}

// per-pixel pcsim given ss, raw dots vs class means, target, mean norms
__device__ __forceinline__ float pc_one(float ss, float d0, float d1, int t,
                                        float nm0, float nm1) {
  const float n = sqrtf(ss);
  const float inv = 1.f / fmaxf(n, 1e-12f);
  const float na = n * inv;  // == |feat| after normalize
  const float c0 = (d0 * inv) / fmaxf(na * nm0, 1e-8f);
  const float c1 = (d1 * inv) / fmaxf(na * nm1, 1e-8f);
  return expf((t == 1) ? (c1 - c0) : (c0 - c1));
}

// grid (SLICES2, NBATCH); 1 float4 iteration per thread, immediate-consume loads.
__global__ __launch_bounds__(TPB) void k_pass2(const float* __restrict__ S,
                                               const float* __restrict__ T,
                                               const int* __restrict__ tgt,
                                               float* __restrict__ ws) {
  __shared__ float sm[68];   // [0..63] means (S0,S1,T0,T1 x 16ch), [64..67] mean norms
  __shared__ float red[4];
  const int b = blockIdx.y;
  const int slice = blockIdx.x;
  const int tid = threadIdx.x;

  if (tid < 64) {
    const int t = tid >> 5, cls = (tid >> 4) & 1, ch = tid & 15;
    const float n1v = ws[WS_N1 + b];
    const float cnt = (cls ? n1v : ((float)HW - n1v)) + 1e-6f;
    const float s = ws[(t ? WS_SUMS_T : WS_SUMS_S) + b * 32 + cls * 16 + ch];
    sm[tid] = s / cnt;
  }
  __syncthreads();
  if (tid < 4) {  // tid = t*2+cls
    float ss = 0.f;
    const int base_ = (tid >> 1) * 32 + (tid & 1) * 16;
#pragma unroll
    for (int c = 0; c < NCH; ++c) { const float v = sm[base_ + c]; ss = fmaf(v, v, ss); }
    sm[64 + tid] = sqrtf(ss);
  }
  __syncthreads();

  const int pxb = HW / SLICES2;  // 1024
  const int p = slice * pxb + tid * 4;
  const float* Sb = S + (size_t)b * NCH * HW;
  const float* Tb = T + (size_t)b * NCH * HW;
  const int4 tv = *(const int4*)(tgt + (size_t)b * HW + p);

  const float nmS0 = sm[64], nmS1 = sm[65], nmT0 = sm[66], nmT1 = sm[67];

  // ---- S: immediate-consume per-channel loads ----
  float4 ssv = {0, 0, 0, 0}, d0 = {0, 0, 0, 0}, d1 = {0, 0, 0, 0};
#pragma unroll
  for (int c = 0; c < NCH; ++c) {
    const float4 x = *(const float4*)(Sb + (size_t)c * HW + p);
    const float w0 = sm[c], w1 = sm[16 + c];
    ssv.x = fmaf(x.x, x.x, ssv.x); ssv.y = fmaf(x.y, x.y, ssv.y);
    ssv.z = fmaf(x.z, x.z, ssv.z); ssv.w = fmaf(x.w, x.w, ssv.w);
    d0.x = fmaf(x.x, w0, d0.x); d0.y = fmaf(x.y, w0, d0.y);
    d0.z = fmaf(x.z, w0, d0.z); d0.w = fmaf(x.w, w0, d0.w);
    d1.x = fmaf(x.x, w1, d1.x); d1.y = fmaf(x.y, w1, d1.y);
    d1.z = fmaf(x.z, w1, d1.z); d1.w = fmaf(x.w, w1, d1.w);
  }
  const float pcS0 = pc_one(ssv.x, d0.x, d1.x, tv.x, nmS0, nmS1);
  const float pcS1 = pc_one(ssv.y, d0.y, d1.y, tv.y, nmS0, nmS1);
  const float pcS2 = pc_one(ssv.z, d0.z, d1.z, tv.z, nmS0, nmS1);
  const float pcS3 = pc_one(ssv.w, d0.w, d1.w, tv.w, nmS0, nmS1);

  // ---- T ----
  ssv = {0, 0, 0, 0}; d0 = {0, 0, 0, 0}; d1 = {0, 0, 0, 0};
#pragma unroll
  for (int c = 0; c < NCH; ++c) {
    const float4 x = *(const float4*)(Tb + (size_t)c * HW + p);
    const float w0 = sm[32 + c], w1 = sm[48 + c];
    ssv.x = fmaf(x.x, x.x, ssv.x); ssv.y = fmaf(x.y, x.y, ssv.y);
    ssv.z = fmaf(x.z, x.z, ssv.z); ssv.w = fmaf(x.w, x.w, ssv.w);
    d0.x = fmaf(x.x, w0, d0.x); d0.y = fmaf(x.y, w0, d0.y);
    d0.z = fmaf(x.z, w0, d0.z); d0.w = fmaf(x.w, w0, d0.w);
    d1.x = fmaf(x.x, w1, d1.x); d1.y = fmaf(x.y, w1, d1.y);
    d1.z = fmaf(x.z, w1, d1.z); d1.w = fmaf(x.w, w1, d1.w);
  }
  const float pcT0 = pc_one(ssv.x, d0.x, d1.x, tv.x, nmT0, nmT1);
  const float pcT1 = pc_one(ssv.y, d0.y, d1.y, tv.y, nmT0, nmT1);
  const float pcT2 = pc_one(ssv.z, d0.z, d1.z, tv.z, nmT0, nmT1);
  const float pcT3 = pc_one(ssv.w, d0.w, d1.w, tv.w, nmT0, nmT1);

  const float e0 = pcS0 - pcT0, e1 = pcS1 - pcT1;
  const float e2 = pcS2 - pcT2, e3 = pcS3 - pcT3;
  float lacc = e0 * e0 + e1 * e1 + e2 * e2 + e3 * e3;

  lacc = wave_sum(lacc);
  if ((tid & 63) == 0) red[tid >> 6] = lacc;
  __syncthreads();
  if (tid == 0)
    atomicAdd(ws + WS_LOSS + b, red[0] + red[1] + red[2] + red[3]);
}

__global__ void k_final(const float* __restrict__ ws, float* __restrict__ out) {
  float s = 0.f;
  for (int b = 0; b < NBATCH; ++b) s += ws[WS_LOSS + b];
  out[0] = s * (1.f / 2097152.f);  // N = 32*256*256 = 2^21, exact
}

extern "C" void kernel_launch(void* const* d_in, const int* in_sizes, int n_in,
                              void* d_out, int out_size, void* d_ws, size_t ws_size,
                              hipStream_t stream) {
  const float* S = (const float*)d_in[0];
  const float* T = (const float*)d_in[1];
  const int* tgt = (const int*)d_in[2];
  float* ws = (float*)d_ws;
  float* out = (float*)d_out;

  hipMemsetAsync(d_ws, 0, WS_FLOATS * sizeof(float), stream);
  dim3 g1(SLICES1, NBATCH, 2);
  k_sums<<<g1, TPB, 0, stream>>>(S, T, tgt, ws);
  dim3 g2(SLICES2, NBATCH);
  k_pass2<<<g2, TPB, 0, stream>>>(S, T, tgt, ws);
  k_final<<<1, 1, 0, stream>>>(ws, out);
}